// Round 4
// baseline (392.656 us; speedup 1.0000x reference)
//
#include <hip/hip_runtime.h>
#include <hip/hip_bf16.h>
#include <math.h>

typedef __attribute__((ext_vector_type(8))) short short8;
typedef __attribute__((ext_vector_type(4))) float f32x4;

#define VOCAB 8192
#define NSAMP 8192
#define INTER 4352
#define EMB   512

// ---- workspace layout (bytes) ----
#define OFF_CNT    0            // 8192*4   = 32768
#define OFF_RANK   32768        // 8192*4   = 32768
#define OFF_CNTC   65536        // 8192*4   = 32768
#define OFF_NUSED  98304        // 64
#define OFF_A1     98368        // 4352*4   = 17408
#define OFF_M1     115776       // 17408
#define OFF_A2     133184       // 2048
#define OFF_M2     135232       // 2048
#define OFF_PS1B   137280       // 512*512*4 = 1048576 (transposed [e][block])
#define OFF_PS2B   1185856      // 1048576
#define OFF_W2B    2234432      // 512*4352*2 = 4456448
#define OFF_HACT   6690880      // 8192*4352*2 = 71303168
#define OFF_HPART  77994048     // 8192*512*4 per chunk
#define PART_BYTES 16777216ULL

#define RSENT 0xFFFFFFFFu

__device__ __forceinline__ float gelu_exact(float x) {
    return 0.5f * x * (1.0f + erff(x * 0.70710678118654752f));
}
__device__ __forceinline__ unsigned short f2bf(float x) {
    __hip_bfloat16 b = __float2bfloat16(x);
    return *reinterpret_cast<unsigned short*>(&b);
}
__device__ __forceinline__ void async16(const unsigned short* g, unsigned short* l) {
    __builtin_amdgcn_global_load_lds(
        (const __attribute__((address_space(1))) void*)g,
        (__attribute__((address_space(3))) void*)l, 16, 0, 0);
}

// ---------------- histogram ----------------
__global__ void k_zero_cnt(int* cnt) {
    cnt[blockIdx.x * 256 + threadIdx.x] = 0;
}
__global__ void k_hist(const int* __restrict__ xt, int* __restrict__ cnt) {
    int n = blockIdx.x * 256 + threadIdx.x;
    atomicAdd(&cnt[xt[n]], 1);
}

// ---------------- compaction scan: rank[v], cntc[rank], nUsed ----------------
__global__ __launch_bounds__(1024) void k_scan(const int* __restrict__ cnt,
                                               unsigned int* __restrict__ rank,
                                               int* __restrict__ cntc,
                                               int* __restrict__ nUsed) {
    __shared__ int tsum[1024];
    const int t = threadIdx.x;
    const int base = t * 8;
    int c[8], f[8];
    int4 a = *(const int4*)(cnt + base);
    int4 b = *(const int4*)(cnt + base + 4);
    c[0]=a.x; c[1]=a.y; c[2]=a.z; c[3]=a.w; c[4]=b.x; c[5]=b.y; c[6]=b.z; c[7]=b.w;
    int s = 0;
    #pragma unroll
    for (int j = 0; j < 8; ++j) { f[j] = s; s += (c[j] > 0); }
    tsum[t] = s;
    __syncthreads();
    #pragma unroll
    for (int d = 1; d < 1024; d <<= 1) {
        int v = (t >= d) ? tsum[t - d] : 0;
        __syncthreads();
        tsum[t] += v;
        __syncthreads();
    }
    const int excl = (t == 0) ? 0 : tsum[t - 1];
    // zero cntc everywhere, then scatter used entries
    *(int4*)(cntc + base) = (int4){0,0,0,0};
    *(int4*)(cntc + base + 4) = (int4){0,0,0,0};
    __syncthreads();
    #pragma unroll
    for (int j = 0; j < 8; ++j) {
        if (c[j] > 0) {
            unsigned int r = (unsigned int)(excl + f[j]);
            rank[base + j] = r;
            cntc[r] = c[j];
        } else {
            rank[base + j] = RSENT;
        }
    }
    if (t == 1023) nUsed[0] = tsum[1023];
}

// ---------------- BN1 stats: one wave per channel row, fused finalize ------------
__global__ __launch_bounds__(256) void k_stats1(const float* __restrict__ W1,
                                                const int* __restrict__ cnt,
                                                const float* __restrict__ g1,
                                                float* __restrict__ a1,
                                                float* __restrict__ m1) {
    const int t = threadIdx.x, lane = t & 63, w = t >> 6;
    const int row = blockIdx.x * 4 + w;
    const float* wr = W1 + (size_t)row * VOCAB;
    float s1 = 0.f, s2 = 0.f;
    #pragma unroll 8
    for (int it = 0; it < 32; ++it) {
        int v = it * 256 + lane * 4;
        float4 x = *(const float4*)(wr + v);
        int4 c = *(const int4*)(cnt + v);
        float cx = (float)c.x, cy = (float)c.y, cz = (float)c.z, cw = (float)c.w;
        s1 += cx * x.x + cy * x.y + cz * x.z + cw * x.w;
        s2 += cx * x.x * x.x + cy * x.y * x.y + cz * x.z * x.z + cw * x.w * x.w;
    }
    #pragma unroll
    for (int d = 1; d < 64; d <<= 1) {
        s1 += __shfl_xor(s1, d);
        s2 += __shfl_xor(s2, d);
    }
    if (lane == 0) {
        float m = s1 * (1.f / NSAMP);
        float var = s2 * (1.f / NSAMP) - m * m;
        a1[row] = g1[row] * rsqrtf(var + 1e-5f);
        m1[row] = m;
    }
}

// ------- build compacted Hact[rank[v],i] = bf16(gelu(a1*(W1[i,v]-m1)+beta1)) -------
__global__ __launch_bounds__(256) void k_build(const float* __restrict__ W1,
                                               const float* __restrict__ a1,
                                               const float* __restrict__ m1,
                                               const float* __restrict__ beta1,
                                               const unsigned int* __restrict__ rank,
                                               unsigned short* __restrict__ Hact) {
    const int i0 = blockIdx.x * 64;
    const int v0 = blockIdx.y * 256;
    const int t = threadIdx.x;
    const int c0 = (t & 15) * 4;
    const int vg = (t >> 4) * 4;   // 0..60
    float4 av = *(const float4*)(a1 + i0 + c0);
    float4 mv = *(const float4*)(m1 + i0 + c0);
    float4 bv = *(const float4*)(beta1 + i0 + c0);
    const float* ap = (const float*)&av;
    const float* mp = (const float*)&mv;
    const float* bp = (const float*)&bv;
    #pragma unroll
    for (int vi = 0; vi < 4; ++vi) {
        int vb = v0 + vi * 64 + vg;
        float wf[4][4];
        #pragma unroll
        for (int j = 0; j < 4; ++j)
            *(float4*)&wf[j][0] = *(const float4*)(W1 + (size_t)(i0 + c0 + j) * VOCAB + vb);
        #pragma unroll
        for (int k = 0; k < 4; ++k) {
            unsigned int rk = rank[vb + k];
            if (rk != RSENT) {
                ushort4 o;
                o.x = f2bf(gelu_exact(ap[0] * (wf[0][k] - mp[0]) + bp[0]));
                o.y = f2bf(gelu_exact(ap[1] * (wf[1][k] - mp[1]) + bp[1]));
                o.z = f2bf(gelu_exact(ap[2] * (wf[2][k] - mp[2]) + bp[2]));
                o.w = f2bf(gelu_exact(ap[3] * (wf[3][k] - mp[3]) + bp[3]));
                *(ushort4*)&Hact[(size_t)rk * INTER + i0 + c0] = o;
            }
        }
    }
}

// ---------------- W2 fp32 -> bf16 ----------------
__global__ void k_w2bf(const float* __restrict__ W2, unsigned short* __restrict__ W2b) {
    int idx = (blockIdx.x * 256 + threadIdx.x) * 4;
    float4 w = *(const float4*)(W2 + idx);
    ushort4 u;
    u.x = f2bf(w.x); u.y = f2bf(w.y); u.z = f2bf(w.z); u.w = f2bf(w.w);
    *(ushort4*)(W2b + idx) = u;
}

// ------- GEMM: Cp[z] = Hact[0..nUsed,Kz] * W2b[512,Kz]^T (bf16 MFMA, split-K) ------
__global__ __launch_bounds__(256) void k_gemm(const unsigned short* __restrict__ A,
                                              const unsigned short* __restrict__ B,
                                              float* __restrict__ Cp, int kPer,
                                              const int* __restrict__ nUsed) {
    const int m0 = blockIdx.x * 128;
    if (m0 >= nUsed[0]) return;     // compaction early-exit
    __shared__ __align__(16) unsigned short sA[128 * 64];
    __shared__ __align__(16) unsigned short sB[128 * 64];
    const int n0 = blockIdx.y * 128;
    const int kbeg = blockIdx.z * kPer;
    const int kend = kbeg + kPer;
    float* C = Cp + (size_t)blockIdx.z * NSAMP * EMB;
    const int t = threadIdx.x;
    const int lane = t & 63;
    const int wave = t >> 6;
    const int wr = wave >> 1, wc = wave & 1;     // 2x2 waves, each 64x64
    const int mq = lane & 15, kq = lane >> 4;
    const int srow = lane >> 3;                  // staging: 8 rows per call
    const int scol = (lane & 7) * 8;
    f32x4 acc[4][4];
    #pragma unroll
    for (int r = 0; r < 4; ++r)
        #pragma unroll
        for (int c = 0; c < 4; ++c) acc[r][c] = (f32x4){0.f, 0.f, 0.f, 0.f};
    for (int k0 = kbeg; k0 < kend; k0 += 64) {
        #pragma unroll
        for (int p = 0; p < 4; ++p) {
            int r0 = (p * 4 + wave) * 8;
            async16(A + (size_t)(m0 + r0 + srow) * INTER + k0 + scol, &sA[r0 * 64]);
            async16(B + (size_t)(n0 + r0 + srow) * INTER + k0 + scol, &sB[r0 * 64]);
        }
        __syncthreads();
        #pragma unroll
        for (int kk = 0; kk < 64; kk += 32) {
            short8 af[4], bf[4];
            #pragma unroll
            for (int r = 0; r < 4; ++r)
                af[r] = *(const short8*)&sA[(wr * 64 + r * 16 + mq) * 64 + kk + kq * 8];
            #pragma unroll
            for (int c = 0; c < 4; ++c)
                bf[c] = *(const short8*)&sB[(wc * 64 + c * 16 + mq) * 64 + kk + kq * 8];
            #pragma unroll
            for (int r = 0; r < 4; ++r)
                #pragma unroll
                for (int c = 0; c < 4; ++c)
                    acc[r][c] = __builtin_amdgcn_mfma_f32_16x16x32_bf16(af[r], bf[c], acc[r][c], 0, 0, 0);
        }
        __syncthreads();
    }
    #pragma unroll
    for (int r = 0; r < 4; ++r) {
        #pragma unroll
        for (int c = 0; c < 4; ++c) {
            int col = n0 + wc * 64 + c * 16 + mq;
            int rowb = m0 + wr * 64 + r * 16 + kq * 4;
            #pragma unroll
            for (int j = 0; j < 4; ++j)
                C[(size_t)(rowb + j) * EMB + col] = acc[r][c][j];
        }
    }
}

// ------- split-K sum -> h2 + cntc-weighted BN2 partial stats (compacted rows) -------
__global__ __launch_bounds__(256) void k_reduce(const float* hpart,
                                                const int* __restrict__ cntc,
                                                float* h2,
                                                float* __restrict__ ps1,
                                                float* __restrict__ ps2, int S) {
    __shared__ float4 b1[128], b2[128];
    const int v0 = blockIdx.x * 16;
    const int t = threadIdx.x;
    const int half = t >> 7;          // wave-uniform (threads 0-127 / 128-255)
    const int c4 = (t & 127) * 4;     // column (float4)
    float4 acc1 = {0.f, 0.f, 0.f, 0.f}, acc2 = {0.f, 0.f, 0.f, 0.f};
    #pragma unroll
    for (int rp = 0; rp < 8; ++rp) {
        int r = v0 + rp * 2 + half;
        int cw_i = cntc[r];
        if (cw_i > 0) {
            size_t off = (size_t)r * EMB + c4;
            float4 h = *(const float4*)(hpart + off);
            for (int s = 1; s < S; ++s) {
                float4 hs = *(const float4*)(hpart + (size_t)s * NSAMP * EMB + off);
                h.x += hs.x; h.y += hs.y; h.z += hs.z; h.w += hs.w;
            }
            *(float4*)(h2 + off) = h;   // h2 aliases hpart chunk 0 (same thread r/w)
            float w = (float)cw_i;
            acc1.x += w * h.x; acc1.y += w * h.y; acc1.z += w * h.z; acc1.w += w * h.w;
            acc2.x += w * h.x * h.x; acc2.y += w * h.y * h.y;
            acc2.z += w * h.z * h.z; acc2.w += w * h.w * h.w;
        }
    }
    if (half == 1) { b1[t & 127] = acc1; b2[t & 127] = acc2; }
    __syncthreads();
    if (half == 0) {
        float4 o1 = b1[t & 127], o2 = b2[t & 127];
        o1.x += acc1.x; o1.y += acc1.y; o1.z += acc1.z; o1.w += acc1.w;
        o2.x += acc2.x; o2.y += acc2.y; o2.z += acc2.z; o2.w += acc2.w;
        ps1[(size_t)(c4 + 0) * 512 + blockIdx.x] = o1.x;
        ps1[(size_t)(c4 + 1) * 512 + blockIdx.x] = o1.y;
        ps1[(size_t)(c4 + 2) * 512 + blockIdx.x] = o1.z;
        ps1[(size_t)(c4 + 3) * 512 + blockIdx.x] = o1.w;
        ps2[(size_t)(c4 + 0) * 512 + blockIdx.x] = o2.x;
        ps2[(size_t)(c4 + 1) * 512 + blockIdx.x] = o2.y;
        ps2[(size_t)(c4 + 2) * 512 + blockIdx.x] = o2.z;
        ps2[(size_t)(c4 + 3) * 512 + blockIdx.x] = o2.w;
    }
}

// one wave per channel e: coalesced 64-lane reads over 512 block-partials
__global__ __launch_bounds__(256) void k_stats2f(const float* __restrict__ ps1,
                                                 const float* __restrict__ ps2,
                                                 const float* __restrict__ g2,
                                                 float* __restrict__ a2,
                                                 float* __restrict__ m2) {
    const int lane = threadIdx.x & 63;
    const int e = blockIdx.x * 4 + (threadIdx.x >> 6);   // 128 blocks
    float s1 = 0.f, s2 = 0.f;
    #pragma unroll
    for (int k = 0; k < 8; ++k) {
        s1 += ps1[(size_t)e * 512 + k * 64 + lane];
        s2 += ps2[(size_t)e * 512 + k * 64 + lane];
    }
    #pragma unroll
    for (int d = 1; d < 64; d <<= 1) {
        s1 += __shfl_xor(s1, d);
        s2 += __shfl_xor(s2, d);
    }
    if (lane == 0) {
        float m = s1 * (1.f / NSAMP);
        float var = s2 * (1.f / NSAMP) - m * m;
        a2[e] = g2[e] * rsqrtf(var + 1e-5f);
        m2[e] = m;
    }
}

// ---------------- final gather (via rank) + BN2 + gelu ----------------
__global__ __launch_bounds__(256) void k_final(const float* __restrict__ h2,
                                               const int* __restrict__ xt,
                                               const unsigned int* __restrict__ rank,
                                               const float* __restrict__ a2,
                                               const float* __restrict__ m2,
                                               const float* __restrict__ beta2,
                                               float* __restrict__ out) {
    const int t = threadIdx.x;
    const int n = blockIdx.x * 2 + (t >> 7);
    const int e = (t & 127) * 4;
    const unsigned int rk = rank[xt[n]];
    float4 h = *(const float4*)(h2 + (size_t)rk * EMB + e);
    float4 a = *(const float4*)(a2 + e);
    float4 m = *(const float4*)(m2 + e);
    float4 b = *(const float4*)(beta2 + e);
    float4 o;
    o.x = gelu_exact(a.x * (h.x - m.x) + b.x);
    o.y = gelu_exact(a.y * (h.y - m.y) + b.y);
    o.z = gelu_exact(a.z * (h.z - m.z) + b.z);
    o.w = gelu_exact(a.w * (h.w - m.w) + b.w);
    *(float4*)(out + (size_t)n * EMB + e) = o;
}

extern "C" void kernel_launch(void* const* d_in, const int* in_sizes, int n_in,
                              void* d_out, int out_size, void* d_ws, size_t ws_size,
                              hipStream_t stream) {
    const int* xt      = (const int*)d_in[0];
    const float* W1    = (const float*)d_in[1];
    // d_in[2] = b1 (cancels in BN), d_in[6] = b2 (cancels in BN)
    const float* g1    = (const float*)d_in[3];
    const float* beta1 = (const float*)d_in[4];
    const float* W2    = (const float*)d_in[5];
    const float* g2    = (const float*)d_in[7];
    const float* beta2 = (const float*)d_in[8];
    float* out = (float*)d_out;

    char* ws = (char*)d_ws;
    int*   cnt  = (int*)  (ws + OFF_CNT);
    unsigned int* rank = (unsigned int*)(ws + OFF_RANK);
    int*   cntc = (int*)  (ws + OFF_CNTC);
    int*   nUsed= (int*)  (ws + OFF_NUSED);
    float* a1   = (float*)(ws + OFF_A1);
    float* m1   = (float*)(ws + OFF_M1);
    float* a2   = (float*)(ws + OFF_A2);
    float* m2   = (float*)(ws + OFF_M2);
    float* ps1b = (float*)(ws + OFF_PS1B);
    float* ps2b = (float*)(ws + OFF_PS2B);
    unsigned short* W2b  = (unsigned short*)(ws + OFF_W2B);
    unsigned short* Hact = (unsigned short*)(ws + OFF_HACT);
    float* hpart = (float*)(ws + OFF_HPART);
    float* h2 = hpart;   // chunk 0 doubles as the final h2

    // split-K factor chosen deterministically from ws_size (graph-safe)
    int S = 1;
    if (ws_size >= OFF_HPART + 4 * PART_BYTES) S = 4;
    else if (ws_size >= OFF_HPART + 2 * PART_BYTES) S = 2;

    k_zero_cnt<<<32, 256, 0, stream>>>(cnt);
    k_hist<<<32, 256, 0, stream>>>(xt, cnt);
    k_scan<<<1, 1024, 0, stream>>>(cnt, rank, cntc, nUsed);
    k_stats1<<<1088, 256, 0, stream>>>(W1, cnt, g1, a1, m1);
    k_build<<<dim3(68, 32), 256, 0, stream>>>(W1, a1, m1, beta1, rank, Hact);
    k_w2bf<<<2176, 256, 0, stream>>>(W2, W2b);
    k_gemm<<<dim3(64, 4, S), 256, 0, stream>>>(Hact, W2b, hpart, INTER / S, nUsed);
    k_reduce<<<512, 256, 0, stream>>>(hpart, cntc, h2, ps1b, ps2b, S);
    k_stats2f<<<128, 256, 0, stream>>>(ps1b, ps2b, g2, a2, m2);
    k_final<<<4096, 256, 0, stream>>>(h2, xt, rank, a2, m2, beta2, out);
}

// Round 5
// 388.460 us; speedup vs baseline: 1.0108x; 1.0108x over previous
//
#include <hip/hip_runtime.h>
#include <hip/hip_bf16.h>
#include <math.h>

typedef __attribute__((ext_vector_type(8))) short short8;
typedef __attribute__((ext_vector_type(4))) float f32x4;

#define VOCAB 8192
#define NSAMP 8192
#define INTER 4352
#define EMB   512

// ---- workspace layout (bytes) ----
#define OFF_CNT    0            // 8192*4   = 32768
#define OFF_RANK   32768        // 8192*4   = 32768
#define OFF_CNTC   65536        // 8192*4   = 32768
#define OFF_NUSED  98304        // 64
#define OFF_A1     98368        // 4352*4   = 17408
#define OFF_M1     115776       // 17408
#define OFF_A2     133184       // 2048
#define OFF_M2     135232       // 2048
#define OFF_PS1B   137280       // 512*512*4 = 1048576 (transposed [e][block])
#define OFF_PS2B   1185856      // 1048576
#define OFF_W2B    2234432      // 512*4352*2 = 4456448
#define OFF_HACT   6690880      // 8192*4352*2 = 71303168
#define OFF_HPART  77994048     // 8192*512*4 per chunk
#define PART_BYTES 16777216ULL

#define RSENT 0xFFFFFFFFu

__device__ __forceinline__ float gelu_exact(float x) {
    return 0.5f * x * (1.0f + erff(x * 0.70710678118654752f));
}
__device__ __forceinline__ unsigned short f2bf(float x) {
    __hip_bfloat16 b = __float2bfloat16(x);
    return *reinterpret_cast<unsigned short*>(&b);
}
__device__ __forceinline__ void async16(const unsigned short* g, unsigned short* l) {
    __builtin_amdgcn_global_load_lds(
        (const __attribute__((address_space(1))) void*)g,
        (__attribute__((address_space(3))) void*)l, 16, 0, 0);
}

// ---------------- histogram ----------------
__global__ void k_zero_cnt(int* cnt) {
    cnt[blockIdx.x * 256 + threadIdx.x] = 0;
}
__global__ void k_hist(const int* __restrict__ xt, int* __restrict__ cnt) {
    int n = blockIdx.x * 256 + threadIdx.x;
    atomicAdd(&cnt[xt[n]], 1);
}

// ---------------- compaction scan: rank[v], cntc[rank], nUsed ----------------
// wave-shuffle scan: 2 barriers total
__global__ __launch_bounds__(1024) void k_scan(const int* __restrict__ cnt,
                                               unsigned int* __restrict__ rank,
                                               int* __restrict__ cntc,
                                               int* __restrict__ nUsed) {
    __shared__ int wsum[16];
    __shared__ int woff[16];
    const int t = threadIdx.x, lane = t & 63, w = t >> 6;
    const int base = t * 8;
    int c[8], f[8];
    int4 a = *(const int4*)(cnt + base);
    int4 b = *(const int4*)(cnt + base + 4);
    c[0]=a.x; c[1]=a.y; c[2]=a.z; c[3]=a.w; c[4]=b.x; c[5]=b.y; c[6]=b.z; c[7]=b.w;
    *(int4*)(cntc + base) = (int4){0,0,0,0};
    *(int4*)(cntc + base + 4) = (int4){0,0,0,0};
    int s = 0;
    #pragma unroll
    for (int j = 0; j < 8; ++j) { f[j] = s; s += (c[j] > 0); }
    int x = s;   // inclusive within wave
    #pragma unroll
    for (int d = 1; d < 64; d <<= 1) {
        int v = __shfl_up(x, d);
        if (lane >= d) x += v;
    }
    if (lane == 63) wsum[w] = x;
    __syncthreads();
    if (t < 16) {
        int o = wsum[t], y = o;
        #pragma unroll
        for (int d = 1; d < 16; d <<= 1) {
            int v = __shfl_up(y, d);
            if (t >= d) y += v;
        }
        woff[t] = y - o;
        if (t == 15) nUsed[0] = y;
    }
    __syncthreads();
    const int ebase = woff[w] + (x - s);
    #pragma unroll
    for (int j = 0; j < 8; ++j) {
        if (c[j] > 0) {
            unsigned int r = (unsigned int)(ebase + f[j]);
            rank[base + j] = r;
            cntc[r] = c[j];
        } else {
            rank[base + j] = RSENT;
        }
    }
}

// ---------------- BN1 stats: one wave per channel row, fused finalize ------------
__global__ __launch_bounds__(256) void k_stats1(const float* __restrict__ W1,
                                                const int* __restrict__ cnt,
                                                const float* __restrict__ g1,
                                                float* __restrict__ a1,
                                                float* __restrict__ m1) {
    const int t = threadIdx.x, lane = t & 63, w = t >> 6;
    const int row = blockIdx.x * 4 + w;
    const float* wr = W1 + (size_t)row * VOCAB;
    float s1 = 0.f, s2 = 0.f;
    #pragma unroll 8
    for (int it = 0; it < 32; ++it) {
        int v = it * 256 + lane * 4;
        float4 x = *(const float4*)(wr + v);
        int4 c = *(const int4*)(cnt + v);
        float cx = (float)c.x, cy = (float)c.y, cz = (float)c.z, cw = (float)c.w;
        s1 += cx * x.x + cy * x.y + cz * x.z + cw * x.w;
        s2 += cx * x.x * x.x + cy * x.y * x.y + cz * x.z * x.z + cw * x.w * x.w;
    }
    #pragma unroll
    for (int d = 1; d < 64; d <<= 1) {
        s1 += __shfl_xor(s1, d);
        s2 += __shfl_xor(s2, d);
    }
    if (lane == 0) {
        float m = s1 * (1.f / NSAMP);
        float var = s2 * (1.f / NSAMP) - m * m;
        a1[row] = g1[row] * rsqrtf(var + 1e-5f);
        m1[row] = m;
    }
}

// ------- build compacted Hact[rank[v],i] = bf16(gelu(a1*(W1[i,v]-m1)+beta1)) -------
__global__ __launch_bounds__(256) void k_build(const float* __restrict__ W1,
                                               const float* __restrict__ a1,
                                               const float* __restrict__ m1,
                                               const float* __restrict__ beta1,
                                               const unsigned int* __restrict__ rank,
                                               unsigned short* __restrict__ Hact) {
    const int i0 = blockIdx.x * 64;
    const int v0 = blockIdx.y * 256;
    const int t = threadIdx.x;
    const int c0 = (t & 15) * 4;
    const int vg = (t >> 4) * 4;   // 0..60
    float4 av = *(const float4*)(a1 + i0 + c0);
    float4 mv = *(const float4*)(m1 + i0 + c0);
    float4 bv = *(const float4*)(beta1 + i0 + c0);
    const float* ap = (const float*)&av;
    const float* mp = (const float*)&mv;
    const float* bp = (const float*)&bv;
    #pragma unroll
    for (int vi = 0; vi < 4; ++vi) {
        int vb = v0 + vi * 64 + vg;
        float wf[4][4];
        #pragma unroll
        for (int j = 0; j < 4; ++j)
            *(float4*)&wf[j][0] = *(const float4*)(W1 + (size_t)(i0 + c0 + j) * VOCAB + vb);
        #pragma unroll
        for (int k = 0; k < 4; ++k) {
            unsigned int rk = rank[vb + k];
            if (rk != RSENT) {
                ushort4 o;
                o.x = f2bf(gelu_exact(ap[0] * (wf[0][k] - mp[0]) + bp[0]));
                o.y = f2bf(gelu_exact(ap[1] * (wf[1][k] - mp[1]) + bp[1]));
                o.z = f2bf(gelu_exact(ap[2] * (wf[2][k] - mp[2]) + bp[2]));
                o.w = f2bf(gelu_exact(ap[3] * (wf[3][k] - mp[3]) + bp[3]));
                *(ushort4*)&Hact[(size_t)rk * INTER + i0 + c0] = o;
            }
        }
    }
}

// ---------------- W2 fp32 -> bf16 ----------------
__global__ void k_w2bf(const float* __restrict__ W2, unsigned short* __restrict__ W2b) {
    int idx = (blockIdx.x * 256 + threadIdx.x) * 4;
    float4 w = *(const float4*)(W2 + idx);
    ushort4 u;
    u.x = f2bf(w.x); u.y = f2bf(w.y); u.z = f2bf(w.z); u.w = f2bf(w.w);
    *(ushort4*)(W2b + idx) = u;
}

// ------- GEMM: Cp[z] = Hact[0..nUsed,Kz] * W2b[512,Kz]^T (bf16 MFMA, split-K) ------
// LDS layout XOR-swizzled: 16B group G of row r stored at group G ^ (r & 7).
// Kills the 16-way ds_read_b128 bank conflict of the unswizzled stride-64 layout.
__global__ __launch_bounds__(256) void k_gemm(const unsigned short* __restrict__ A,
                                              const unsigned short* __restrict__ B,
                                              float* __restrict__ Cp, int kPer,
                                              const int* __restrict__ nUsed) {
    const int m0 = blockIdx.x * 128;
    if (m0 >= nUsed[0]) return;     // compaction early-exit
    __shared__ __align__(16) unsigned short sA[128 * 64];
    __shared__ __align__(16) unsigned short sB[128 * 64];
    const int n0 = blockIdx.y * 128;
    const int kbeg = blockIdx.z * kPer;
    const int kend = kbeg + kPer;
    float* C = Cp + (size_t)blockIdx.z * NSAMP * EMB;
    const int t = threadIdx.x;
    const int lane = t & 63;
    const int wave = t >> 6;
    const int wr = wave >> 1, wc = wave & 1;     // 2x2 waves, each 64x64
    const int mq = lane & 15, kq = lane >> 4;
    const int srow = lane >> 3;                  // staging row within 8-row group
    const int sgrp = lane & 7;                   // staging 16B-group
    const int scol = ((sgrp ^ srow) * 8);        // swizzled global column (shorts)
    const int swz = mq & 7;                      // fragment-read swizzle
    f32x4 acc[4][4];
    #pragma unroll
    for (int r = 0; r < 4; ++r)
        #pragma unroll
        for (int c = 0; c < 4; ++c) acc[r][c] = (f32x4){0.f, 0.f, 0.f, 0.f};
    for (int k0 = kbeg; k0 < kend; k0 += 64) {
        #pragma unroll
        for (int p = 0; p < 4; ++p) {
            int r0 = (p * 4 + wave) * 8;
            async16(A + (size_t)(m0 + r0 + srow) * INTER + k0 + scol, &sA[r0 * 64]);
            async16(B + (size_t)(n0 + r0 + srow) * INTER + k0 + scol, &sB[r0 * 64]);
        }
        __syncthreads();
        #pragma unroll
        for (int kk = 0; kk < 64; kk += 32) {
            const int gbase = kq + (kk >> 3);    // 16B-group index before swizzle
            short8 af[4], bf[4];
            #pragma unroll
            for (int r = 0; r < 4; ++r)
                af[r] = *(const short8*)&sA[(wr * 64 + r * 16 + mq) * 64 + ((gbase ^ swz) * 8)];
            #pragma unroll
            for (int c = 0; c < 4; ++c)
                bf[c] = *(const short8*)&sB[(wc * 64 + c * 16 + mq) * 64 + ((gbase ^ swz) * 8)];
            #pragma unroll
            for (int r = 0; r < 4; ++r)
                #pragma unroll
                for (int c = 0; c < 4; ++c)
                    acc[r][c] = __builtin_amdgcn_mfma_f32_16x16x32_bf16(af[r], bf[c], acc[r][c], 0, 0, 0);
        }
        __syncthreads();
    }
    #pragma unroll
    for (int r = 0; r < 4; ++r) {
        #pragma unroll
        for (int c = 0; c < 4; ++c) {
            int col = n0 + wc * 64 + c * 16 + mq;
            int rowb = m0 + wr * 64 + r * 16 + kq * 4;
            #pragma unroll
            for (int j = 0; j < 4; ++j)
                C[(size_t)(rowb + j) * EMB + col] = acc[r][c][j];
        }
    }
}

// ------- split-K sum -> h2 + cntc-weighted BN2 partial stats (compacted rows) -------
__global__ __launch_bounds__(256) void k_reduce(const float* hpart,
                                                const int* __restrict__ cntc,
                                                float* h2,
                                                float* __restrict__ ps1,
                                                float* __restrict__ ps2, int S) {
    __shared__ float4 b1[128], b2[128];
    const int v0 = blockIdx.x * 16;
    const int t = threadIdx.x;
    const int half = t >> 7;          // wave-uniform (threads 0-127 / 128-255)
    const int c4 = (t & 127) * 4;     // column (float4)
    float4 acc1 = {0.f, 0.f, 0.f, 0.f}, acc2 = {0.f, 0.f, 0.f, 0.f};
    #pragma unroll
    for (int rp = 0; rp < 8; ++rp) {
        int r = v0 + rp * 2 + half;
        int cw_i = cntc[r];
        if (cw_i > 0) {
            size_t off = (size_t)r * EMB + c4;
            float4 h = *(const float4*)(hpart + off);
            for (int s = 1; s < S; ++s) {
                float4 hs = *(const float4*)(hpart + (size_t)s * NSAMP * EMB + off);
                h.x += hs.x; h.y += hs.y; h.z += hs.z; h.w += hs.w;
            }
            *(float4*)(h2 + off) = h;   // h2 aliases hpart chunk 0 (same thread r/w)
            float w = (float)cw_i;
            acc1.x += w * h.x; acc1.y += w * h.y; acc1.z += w * h.z; acc1.w += w * h.w;
            acc2.x += w * h.x * h.x; acc2.y += w * h.y * h.y;
            acc2.z += w * h.z * h.z; acc2.w += w * h.w * h.w;
        }
    }
    if (half == 1) { b1[t & 127] = acc1; b2[t & 127] = acc2; }
    __syncthreads();
    if (half == 0) {
        float4 o1 = b1[t & 127], o2 = b2[t & 127];
        o1.x += acc1.x; o1.y += acc1.y; o1.z += acc1.z; o1.w += acc1.w;
        o2.x += acc2.x; o2.y += acc2.y; o2.z += acc2.z; o2.w += acc2.w;
        ps1[(size_t)(c4 + 0) * 512 + blockIdx.x] = o1.x;
        ps1[(size_t)(c4 + 1) * 512 + blockIdx.x] = o1.y;
        ps1[(size_t)(c4 + 2) * 512 + blockIdx.x] = o1.z;
        ps1[(size_t)(c4 + 3) * 512 + blockIdx.x] = o1.w;
        ps2[(size_t)(c4 + 0) * 512 + blockIdx.x] = o2.x;
        ps2[(size_t)(c4 + 1) * 512 + blockIdx.x] = o2.y;
        ps2[(size_t)(c4 + 2) * 512 + blockIdx.x] = o2.z;
        ps2[(size_t)(c4 + 3) * 512 + blockIdx.x] = o2.w;
    }
}

// one wave per channel e: coalesced 64-lane reads over 512 block-partials
__global__ __launch_bounds__(256) void k_stats2f(const float* __restrict__ ps1,
                                                 const float* __restrict__ ps2,
                                                 const float* __restrict__ g2,
                                                 float* __restrict__ a2,
                                                 float* __restrict__ m2) {
    const int lane = threadIdx.x & 63;
    const int e = blockIdx.x * 4 + (threadIdx.x >> 6);   // 128 blocks
    float s1 = 0.f, s2 = 0.f;
    #pragma unroll
    for (int k = 0; k < 8; ++k) {
        s1 += ps1[(size_t)e * 512 + k * 64 + lane];
        s2 += ps2[(size_t)e * 512 + k * 64 + lane];
    }
    #pragma unroll
    for (int d = 1; d < 64; d <<= 1) {
        s1 += __shfl_xor(s1, d);
        s2 += __shfl_xor(s2, d);
    }
    if (lane == 0) {
        float m = s1 * (1.f / NSAMP);
        float var = s2 * (1.f / NSAMP) - m * m;
        a2[e] = g2[e] * rsqrtf(var + 1e-5f);
        m2[e] = m;
    }
}

// ---------------- final gather (via rank) + BN2 + gelu ----------------
__global__ __launch_bounds__(256) void k_final(const float* __restrict__ h2,
                                               const int* __restrict__ xt,
                                               const unsigned int* __restrict__ rank,
                                               const float* __restrict__ a2,
                                               const float* __restrict__ m2,
                                               const float* __restrict__ beta2,
                                               float* __restrict__ out) {
    const int t = threadIdx.x;
    const int n = blockIdx.x * 2 + (t >> 7);
    const int e = (t & 127) * 4;
    const unsigned int rk = rank[xt[n]];
    float4 h = *(const float4*)(h2 + (size_t)rk * EMB + e);
    float4 a = *(const float4*)(a2 + e);
    float4 m = *(const float4*)(m2 + e);
    float4 b = *(const float4*)(beta2 + e);
    float4 o;
    o.x = gelu_exact(a.x * (h.x - m.x) + b.x);
    o.y = gelu_exact(a.y * (h.y - m.y) + b.y);
    o.z = gelu_exact(a.z * (h.z - m.z) + b.z);
    o.w = gelu_exact(a.w * (h.w - m.w) + b.w);
    *(float4*)(out + (size_t)n * EMB + e) = o;
}

extern "C" void kernel_launch(void* const* d_in, const int* in_sizes, int n_in,
                              void* d_out, int out_size, void* d_ws, size_t ws_size,
                              hipStream_t stream) {
    const int* xt      = (const int*)d_in[0];
    const float* W1    = (const float*)d_in[1];
    // d_in[2] = b1 (cancels in BN), d_in[6] = b2 (cancels in BN)
    const float* g1    = (const float*)d_in[3];
    const float* beta1 = (const float*)d_in[4];
    const float* W2    = (const float*)d_in[5];
    const float* g2    = (const float*)d_in[7];
    const float* beta2 = (const float*)d_in[8];
    float* out = (float*)d_out;

    char* ws = (char*)d_ws;
    int*   cnt  = (int*)  (ws + OFF_CNT);
    unsigned int* rank = (unsigned int*)(ws + OFF_RANK);
    int*   cntc = (int*)  (ws + OFF_CNTC);
    int*   nUsed= (int*)  (ws + OFF_NUSED);
    float* a1   = (float*)(ws + OFF_A1);
    float* m1   = (float*)(ws + OFF_M1);
    float* a2   = (float*)(ws + OFF_A2);
    float* m2   = (float*)(ws + OFF_M2);
    float* ps1b = (float*)(ws + OFF_PS1B);
    float* ps2b = (float*)(ws + OFF_PS2B);
    unsigned short* W2b  = (unsigned short*)(ws + OFF_W2B);
    unsigned short* Hact = (unsigned short*)(ws + OFF_HACT);
    float* hpart = (float*)(ws + OFF_HPART);
    float* h2 = hpart;   // chunk 0 doubles as the final h2

    // split-K factor chosen deterministically from ws_size (graph-safe)
    int S = 1;
    if (ws_size >= OFF_HPART + 4 * PART_BYTES) S = 4;
    else if (ws_size >= OFF_HPART + 2 * PART_BYTES) S = 2;

    k_zero_cnt<<<32, 256, 0, stream>>>(cnt);
    k_hist<<<32, 256, 0, stream>>>(xt, cnt);
    k_scan<<<1, 1024, 0, stream>>>(cnt, rank, cntc, nUsed);
    k_stats1<<<1088, 256, 0, stream>>>(W1, cnt, g1, a1, m1);
    k_build<<<dim3(68, 32), 256, 0, stream>>>(W1, a1, m1, beta1, rank, Hact);
    k_w2bf<<<2176, 256, 0, stream>>>(W2, W2b);
    k_gemm<<<dim3(64, 4, S), 256, 0, stream>>>(Hact, W2b, hpart, INTER / S, nUsed);
    k_reduce<<<512, 256, 0, stream>>>(hpart, cntc, h2, ps1b, ps2b, S);
    k_stats2f<<<128, 256, 0, stream>>>(ps1b, ps2b, g2, a2, m2);
    k_final<<<4096, 256, 0, stream>>>(h2, xt, rank, a2, m2, beta2, out);
}

// Round 6
// 356.306 us; speedup vs baseline: 1.1020x; 1.0902x over previous
//
#include <hip/hip_runtime.h>
#include <hip/hip_bf16.h>
#include <math.h>

typedef __attribute__((ext_vector_type(8))) short short8;
typedef __attribute__((ext_vector_type(4))) float f32x4;

#define VOCAB 8192
#define NSAMP 8192
#define INTER 4352
#define EMB   512

// ---- workspace layout (bytes) ----
#define OFF_CNT    0            // 8192*4   = 32768
#define OFF_A1     32768        // 4352*4   = 17408
#define OFF_M1     50176        // 17408
#define OFF_A2     67584        // 2048
#define OFF_M2     69632        // 2048
#define OFF_PS1B   71680        // 512*512*4 = 1048576 (transposed [e][block])
#define OFF_PS2B   1120256      // 1048576
#define OFF_W2B    2168832      // 512*4352*2 = 4456448
#define OFF_HACT   6625280      // 8192*4352*2 = 71303168
#define OFF_HPART  77928448     // 8192*512*4 per chunk
#define PART_BYTES 16777216ULL

__device__ __forceinline__ float gelu_exact(float x) {
    return 0.5f * x * (1.0f + erff(x * 0.70710678118654752f));
}
__device__ __forceinline__ unsigned short f2bf(float x) {
    __hip_bfloat16 b = __float2bfloat16(x);
    return *reinterpret_cast<unsigned short*>(&b);
}
__device__ __forceinline__ void async16(const unsigned short* g, unsigned short* l) {
    __builtin_amdgcn_global_load_lds(
        (const __attribute__((address_space(1))) void*)g,
        (__attribute__((address_space(3))) void*)l, 16, 0, 0);
}

// ---------------- histogram ----------------
__global__ void k_zero_cnt(int* cnt) {
    cnt[blockIdx.x * 256 + threadIdx.x] = 0;
}
__global__ void k_hist(const int* __restrict__ xt, int* __restrict__ cnt) {
    int n = blockIdx.x * 256 + threadIdx.x;
    atomicAdd(&cnt[xt[n]], 1);
}

// ---------------- BN1 stats: one wave per channel row, fused finalize ------------
__global__ __launch_bounds__(256) void k_stats1(const float* __restrict__ W1,
                                                const int* __restrict__ cnt,
                                                const float* __restrict__ g1,
                                                float* __restrict__ a1,
                                                float* __restrict__ m1) {
    const int t = threadIdx.x, lane = t & 63, w = t >> 6;
    const int row = blockIdx.x * 4 + w;
    const float* wr = W1 + (size_t)row * VOCAB;
    float s1 = 0.f, s2 = 0.f;
    #pragma unroll 8
    for (int it = 0; it < 32; ++it) {
        int v = it * 256 + lane * 4;
        float4 x = *(const float4*)(wr + v);
        int4 c = *(const int4*)(cnt + v);
        float cx = (float)c.x, cy = (float)c.y, cz = (float)c.z, cw = (float)c.w;
        s1 += cx * x.x + cy * x.y + cz * x.z + cw * x.w;
        s2 += cx * x.x * x.x + cy * x.y * x.y + cz * x.z * x.z + cw * x.w * x.w;
    }
    #pragma unroll
    for (int d = 1; d < 64; d <<= 1) {
        s1 += __shfl_xor(s1, d);
        s2 += __shfl_xor(s2, d);
    }
    if (lane == 0) {
        float m = s1 * (1.f / NSAMP);
        float var = s2 * (1.f / NSAMP) - m * m;
        a1[row] = g1[row] * rsqrtf(var + 1e-5f);
        m1[row] = m;
    }
}

// ------- build Hact[v,i] = bf16(gelu(a1*(W1[i,v]-m1)+beta1)), all vocab rows -------
__global__ __launch_bounds__(256) void k_build(const float* __restrict__ W1,
                                               const float* __restrict__ a1,
                                               const float* __restrict__ m1,
                                               const float* __restrict__ beta1,
                                               unsigned short* __restrict__ Hact) {
    const int i0 = blockIdx.x * 64;
    const int v0 = blockIdx.y * 256;
    const int t = threadIdx.x;
    const int c0 = (t & 15) * 4;
    const int vg = (t >> 4) * 4;   // 0..60
    float4 av = *(const float4*)(a1 + i0 + c0);
    float4 mv = *(const float4*)(m1 + i0 + c0);
    float4 bv = *(const float4*)(beta1 + i0 + c0);
    const float* ap = (const float*)&av;
    const float* mp = (const float*)&mv;
    const float* bp = (const float*)&bv;
    #pragma unroll
    for (int vi = 0; vi < 4; ++vi) {
        int vb = v0 + vi * 64 + vg;
        float wf[4][4];
        #pragma unroll
        for (int j = 0; j < 4; ++j)
            *(float4*)&wf[j][0] = *(const float4*)(W1 + (size_t)(i0 + c0 + j) * VOCAB + vb);
        #pragma unroll
        for (int k = 0; k < 4; ++k) {
            ushort4 o;
            o.x = f2bf(gelu_exact(ap[0] * (wf[0][k] - mp[0]) + bp[0]));
            o.y = f2bf(gelu_exact(ap[1] * (wf[1][k] - mp[1]) + bp[1]));
            o.z = f2bf(gelu_exact(ap[2] * (wf[2][k] - mp[2]) + bp[2]));
            o.w = f2bf(gelu_exact(ap[3] * (wf[3][k] - mp[3]) + bp[3]));
            *(ushort4*)&Hact[(size_t)(vb + k) * INTER + i0 + c0] = o;
        }
    }
}

// ---------------- W2 fp32 -> bf16 ----------------
__global__ void k_w2bf(const float* __restrict__ W2, unsigned short* __restrict__ W2b) {
    int idx = (blockIdx.x * 256 + threadIdx.x) * 4;
    float4 w = *(const float4*)(W2 + idx);
    ushort4 u;
    u.x = f2bf(w.x); u.y = f2bf(w.y); u.z = f2bf(w.z); u.w = f2bf(w.w);
    *(ushort4*)(W2b + idx) = u;
}

// ------- fat-block GEMM: Cp[z] = Hact[8192,Kz] * W2b[512,Kz]^T (bf16 MFMA) ---------
// Block = 128 M x 512 N (full width), 512 threads = 8 waves (2x4), K-chunk 64.
// LDS: sA 16 KB + sB 64 KB = 80 KB; 1 block/CU; grid (64,1,S) uniform, no early-exit.
// XOR-swizzled LDS groups (16B group G of row r at G ^ (r&7)) — conflict-free reads.
__global__ __launch_bounds__(512) void k_gemm(const unsigned short* __restrict__ A,
                                              const unsigned short* __restrict__ B,
                                              float* __restrict__ Cp, int kPer) {
    __shared__ __align__(16) unsigned short sA[128 * 64];
    __shared__ __align__(16) unsigned short sB[512 * 64];
    const int m0 = blockIdx.x * 128;
    const int kbeg = blockIdx.z * kPer;
    const int kend = kbeg + kPer;
    float* C = Cp + (size_t)blockIdx.z * NSAMP * EMB;
    const int t = threadIdx.x;
    const int lane = t & 63;
    const int wave = t >> 6;                     // 0..7
    const int wr = wave >> 2, wc = wave & 3;     // 2x4 waves, each 64x128
    const int mq = lane & 15, kq = lane >> 4;
    const int srow = lane >> 3;                  // staging row within 8-row group
    const int sgrp = lane & 7;                   // staging 16B-group
    const int scol = (sgrp ^ srow) * 8;          // swizzled global column (shorts)
    const int swz = mq & 7;                      // fragment-read swizzle
    f32x4 acc[4][8];
    #pragma unroll
    for (int r = 0; r < 4; ++r)
        #pragma unroll
        for (int c = 0; c < 8; ++c) acc[r][c] = (f32x4){0.f, 0.f, 0.f, 0.f};
    for (int k0 = kbeg; k0 < kend; k0 += 64) {
        // A: 128 rows, wave w stages rows [w*16, w*16+16)
        #pragma unroll
        for (int p = 0; p < 2; ++p) {
            int r0 = wave * 16 + p * 8;
            async16(A + (size_t)(m0 + r0 + srow) * INTER + k0 + scol, &sA[r0 * 64]);
        }
        // B: 512 rows, wave w stages rows [w*64, w*64+64)
        #pragma unroll
        for (int p = 0; p < 8; ++p) {
            int r0 = wave * 64 + p * 8;
            async16(B + (size_t)(r0 + srow) * INTER + k0 + scol, &sB[r0 * 64]);
        }
        __syncthreads();
        #pragma unroll
        for (int kk = 0; kk < 64; kk += 32) {
            const int gbase = kq + (kk >> 3);
            short8 af[4], bf[8];
            #pragma unroll
            for (int r = 0; r < 4; ++r)
                af[r] = *(const short8*)&sA[(wr * 64 + r * 16 + mq) * 64 + ((gbase ^ swz) * 8)];
            #pragma unroll
            for (int c = 0; c < 8; ++c)
                bf[c] = *(const short8*)&sB[(wc * 128 + c * 16 + mq) * 64 + ((gbase ^ swz) * 8)];
            #pragma unroll
            for (int r = 0; r < 4; ++r)
                #pragma unroll
                for (int c = 0; c < 8; ++c)
                    acc[r][c] = __builtin_amdgcn_mfma_f32_16x16x32_bf16(af[r], bf[c], acc[r][c], 0, 0, 0);
        }
        __syncthreads();
    }
    #pragma unroll
    for (int r = 0; r < 4; ++r) {
        #pragma unroll
        for (int c = 0; c < 8; ++c) {
            int col = wc * 128 + c * 16 + mq;
            int rowb = m0 + wr * 64 + r * 16 + kq * 4;
            #pragma unroll
            for (int j = 0; j < 4; ++j)
                C[(size_t)(rowb + j) * EMB + col] = acc[r][c][j];
        }
    }
}

// ------- split-K sum -> h2 + cnt-weighted BN2 partial stats ----------------
__global__ __launch_bounds__(256) void k_reduce(const float* hpart,
                                                const int* __restrict__ cnt,
                                                float* h2,
                                                float* __restrict__ ps1,
                                                float* __restrict__ ps2, int S) {
    __shared__ float4 b1[128], b2[128];
    const int v0 = blockIdx.x * 16;
    const int t = threadIdx.x;
    const int half = t >> 7;          // wave-uniform (threads 0-127 / 128-255)
    const int c4 = (t & 127) * 4;     // column (float4)
    float4 acc1 = {0.f, 0.f, 0.f, 0.f}, acc2 = {0.f, 0.f, 0.f, 0.f};
    #pragma unroll
    for (int rp = 0; rp < 8; ++rp) {
        int r = v0 + rp * 2 + half;
        int cw_i = cnt[r];
        if (cw_i > 0) {               // unused rows: no sum, no stats, never read later
            size_t off = (size_t)r * EMB + c4;
            float4 h = *(const float4*)(hpart + off);
            for (int s = 1; s < S; ++s) {
                float4 hs = *(const float4*)(hpart + (size_t)s * NSAMP * EMB + off);
                h.x += hs.x; h.y += hs.y; h.z += hs.z; h.w += hs.w;
            }
            *(float4*)(h2 + off) = h;   // h2 aliases hpart chunk 0 (same thread r/w)
            float w = (float)cw_i;
            acc1.x += w * h.x; acc1.y += w * h.y; acc1.z += w * h.z; acc1.w += w * h.w;
            acc2.x += w * h.x * h.x; acc2.y += w * h.y * h.y;
            acc2.z += w * h.z * h.z; acc2.w += w * h.w * h.w;
        }
    }
    if (half == 1) { b1[t & 127] = acc1; b2[t & 127] = acc2; }
    __syncthreads();
    if (half == 0) {
        float4 o1 = b1[t & 127], o2 = b2[t & 127];
        o1.x += acc1.x; o1.y += acc1.y; o1.z += acc1.z; o1.w += acc1.w;
        o2.x += acc2.x; o2.y += acc2.y; o2.z += acc2.z; o2.w += acc2.w;
        ps1[(size_t)(c4 + 0) * 512 + blockIdx.x] = o1.x;
        ps1[(size_t)(c4 + 1) * 512 + blockIdx.x] = o1.y;
        ps1[(size_t)(c4 + 2) * 512 + blockIdx.x] = o1.z;
        ps1[(size_t)(c4 + 3) * 512 + blockIdx.x] = o1.w;
        ps2[(size_t)(c4 + 0) * 512 + blockIdx.x] = o2.x;
        ps2[(size_t)(c4 + 1) * 512 + blockIdx.x] = o2.y;
        ps2[(size_t)(c4 + 2) * 512 + blockIdx.x] = o2.z;
        ps2[(size_t)(c4 + 3) * 512 + blockIdx.x] = o2.w;
    }
}

// one wave per channel e: coalesced 64-lane reads over 512 block-partials
__global__ __launch_bounds__(256) void k_stats2f(const float* __restrict__ ps1,
                                                 const float* __restrict__ ps2,
                                                 const float* __restrict__ g2,
                                                 float* __restrict__ a2,
                                                 float* __restrict__ m2) {
    const int lane = threadIdx.x & 63;
    const int e = blockIdx.x * 4 + (threadIdx.x >> 6);   // 128 blocks
    float s1 = 0.f, s2 = 0.f;
    #pragma unroll
    for (int k = 0; k < 8; ++k) {
        s1 += ps1[(size_t)e * 512 + k * 64 + lane];
        s2 += ps2[(size_t)e * 512 + k * 64 + lane];
    }
    #pragma unroll
    for (int d = 1; d < 64; d <<= 1) {
        s1 += __shfl_xor(s1, d);
        s2 += __shfl_xor(s2, d);
    }
    if (lane == 0) {
        float m = s1 * (1.f / NSAMP);
        float var = s2 * (1.f / NSAMP) - m * m;
        a2[e] = g2[e] * rsqrtf(var + 1e-5f);
        m2[e] = m;
    }
}

// ---------------- final gather + BN2 + gelu ----------------
__global__ __launch_bounds__(256) void k_final(const float* __restrict__ h2,
                                               const int* __restrict__ xt,
                                               const float* __restrict__ a2,
                                               const float* __restrict__ m2,
                                               const float* __restrict__ beta2,
                                               float* __restrict__ out) {
    const int t = threadIdx.x;
    const int n = blockIdx.x * 2 + (t >> 7);
    const int e = (t & 127) * 4;
    const int v = xt[n];
    float4 h = *(const float4*)(h2 + (size_t)v * EMB + e);
    float4 a = *(const float4*)(a2 + e);
    float4 m = *(const float4*)(m2 + e);
    float4 b = *(const float4*)(beta2 + e);
    float4 o;
    o.x = gelu_exact(a.x * (h.x - m.x) + b.x);
    o.y = gelu_exact(a.y * (h.y - m.y) + b.y);
    o.z = gelu_exact(a.z * (h.z - m.z) + b.z);
    o.w = gelu_exact(a.w * (h.w - m.w) + b.w);
    *(float4*)(out + (size_t)n * EMB + e) = o;
}

extern "C" void kernel_launch(void* const* d_in, const int* in_sizes, int n_in,
                              void* d_out, int out_size, void* d_ws, size_t ws_size,
                              hipStream_t stream) {
    const int* xt      = (const int*)d_in[0];
    const float* W1    = (const float*)d_in[1];
    // d_in[2] = b1 (cancels in BN), d_in[6] = b2 (cancels in BN)
    const float* g1    = (const float*)d_in[3];
    const float* beta1 = (const float*)d_in[4];
    const float* W2    = (const float*)d_in[5];
    const float* g2    = (const float*)d_in[7];
    const float* beta2 = (const float*)d_in[8];
    float* out = (float*)d_out;

    char* ws = (char*)d_ws;
    int*   cnt  = (int*)  (ws + OFF_CNT);
    float* a1   = (float*)(ws + OFF_A1);
    float* m1   = (float*)(ws + OFF_M1);
    float* a2   = (float*)(ws + OFF_A2);
    float* m2   = (float*)(ws + OFF_M2);
    float* ps1b = (float*)(ws + OFF_PS1B);
    float* ps2b = (float*)(ws + OFF_PS2B);
    unsigned short* W2b  = (unsigned short*)(ws + OFF_W2B);
    unsigned short* Hact = (unsigned short*)(ws + OFF_HACT);
    float* hpart = (float*)(ws + OFF_HPART);
    float* h2 = hpart;   // chunk 0 doubles as the final h2

    // split-K factor chosen deterministically from ws_size (graph-safe)
    int S = 1;
    if (ws_size >= OFF_HPART + 4 * PART_BYTES) S = 4;
    else if (ws_size >= OFF_HPART + 2 * PART_BYTES) S = 2;

    k_zero_cnt<<<32, 256, 0, stream>>>(cnt);
    k_hist<<<32, 256, 0, stream>>>(xt, cnt);
    k_stats1<<<1088, 256, 0, stream>>>(W1, cnt, g1, a1, m1);
    k_build<<<dim3(68, 32), 256, 0, stream>>>(W1, a1, m1, beta1, Hact);
    k_w2bf<<<2176, 256, 0, stream>>>(W2, W2b);
    k_gemm<<<dim3(64, 1, S), 512, 0, stream>>>(Hact, W2b, hpart, INTER / S);
    k_reduce<<<512, 256, 0, stream>>>(hpart, cnt, h2, ps1b, ps2b, S);
    k_stats2f<<<128, 256, 0, stream>>>(ps1b, ps2b, g2, a2, m2);
    k_final<<<4096, 256, 0, stream>>>(h2, xt, a2, m2, beta2, out);
}